// Round 2
// baseline (317.509 us; speedup 1.0000x reference)
//
#include <hip/hip_runtime.h>

#define D 64
#define SLOTS 16    // fixed pr slots per node (slot0 self + 14 edges + chain/pad)
#define MAXCONT 69632

typedef unsigned int u32;
typedef unsigned short u16;
typedef short bf8v __attribute__((ext_vector_type(8)));
typedef float f4v __attribute__((ext_vector_type(4)));

__device__ __forceinline__ float bf_lo(u32 p) { return __uint_as_float(p << 16); }
__device__ __forceinline__ float bf_hi(u32 p) { return __uint_as_float(p & 0xffff0000u); }
__device__ __forceinline__ u32 bf_rne(float f) {
    u32 u = __float_as_uint(f);
    return (u + 0x7fffu + ((u >> 16) & 1u)) >> 16;
}

// ---------------- pass 1: per-node degree via global atomics ----------------
// cnt zeroed by memsetAsync beforehand. 1M atomics over 100K counters: L2-resident.
__global__ __launch_bounds__(256) void cnt_k(const int* __restrict__ dst,
                                             int* __restrict__ cnt, int E) {
    int idx = blockIdx.x * 256 + threadIdx.x;
    int stride = gridDim.x * 256;
    int nv = E >> 2;
    const int4* d4 = (const int4*)dst;
    for (int i = idx; i < nv; i += stride) {
        int4 d = d4[i];
        atomicAdd(&cnt[d.x], 1);
        atomicAdd(&cnt[d.y], 1);
        atomicAdd(&cnt[d.z], 1);
        atomicAdd(&cnt[d.w], 1);
    }
    for (int e = (nv << 2) + idx; e < E; e += stride) atomicAdd(&cnt[dst[e]], 1);
}

// ---------------- pass 2: coalesced slot-block init ----------------
// 8 threads per node; thread (node,j) writes pr slots {2j,2j+1} as one int4 at
// flat index node*8+j -> consecutive threads write consecutive 16B: perfect
// coalescing. j==0 does per-node bookkeeping (dinv, cur=1, cbase, chain-region
// pads+links for the ~8% of nodes with deg>14) and shares cbase via shfl.
// Slot content: 0 = (n, dinv^2) self; 1..14 = (n,+0.0) pads (edges overwrite
// in pass 3); 15 = (n,+0.0) pad or (cbase, -0.0) chain link.
__global__ __launch_bounds__(256) void init_k(const int* __restrict__ cnt,
                                              float* __restrict__ dinv,
                                              int* __restrict__ cur,
                                              int* __restrict__ cbase,
                                              int2* __restrict__ pr,
                                              int* __restrict__ ovf, int N) {
    int idx = blockIdx.x * 256 + threadIdx.x;
    int lane = threadIdx.x & 63;
    int node = idx >> 3;
    int j = idx & 7;
    bool valid = node < N;
    int c = valid ? cnt[node] : 0;
    float di = rsqrtf((float)c + 1.0f);
    int nblk = (c > 14) ? (c / 15) : 0;
    int cb = 0;
    if (valid && j == 0) {
        if (nblk) cb = atomicAdd(ovf, nblk);
        dinv[node] = di;
        cur[node] = 1;
        cbase[node] = cb;
        // chain region: blocks cb..cb+nblk-1, 15 payload pads + link at slot15
        for (int k = 0; k < nblk; ++k) {
            int2* blk = pr + ((size_t)N + (size_t)(cb + k)) * SLOTS;
            int4 pad = make_int4(node, 0, node, 0);
            int4* b4 = (int4*)blk;
            b4[0] = pad; b4[1] = pad; b4[2] = pad; b4[3] = pad;
            b4[4] = pad; b4[5] = pad; b4[6] = pad;
            blk[14] = make_int2(node, 0);
            blk[15] = (k < nblk - 1) ? make_int2(cb + k + 1, (int)0x80000000u)
                                     : make_int2(node, 0);
        }
    }
    cb = __shfl(cb, lane & 56, 64);  // broadcast from the j==0 lane of this node
    if (!valid) return;
    int4 v;
    if (j == 0)
        v = make_int4(node, __float_as_int(di * di), node, 0);
    else if (j == 7)
        v = nblk ? make_int4(node, 0, cb, (int)0x80000000u)
                 : make_int4(node, 0, node, 0);
    else
        v = make_int4(node, 0, node, 0);
    ((int4*)pr)[idx] = v;
}

// ---------------- pass 3: direct edge scatter into slots ----------------
__device__ __forceinline__ void scat1(int s, int d, const float* __restrict__ dinv,
                                      int* __restrict__ cur,
                                      const int* __restrict__ cbase,
                                      int2* __restrict__ pr, int N) {
    int pos = atomicAdd(&cur[d], 1);
    float w = dinv[s] * dinv[d];
    size_t phys;
    if (pos < 15) {
        phys = (size_t)d * SLOTS + pos;
    } else {
        int r = pos - 15;
        phys = ((size_t)N + (size_t)(cbase[d] + r / 15)) * SLOTS + (r % 15);
    }
    pr[phys] = make_int2(s, __float_as_int(w));
}

__global__ __launch_bounds__(256) void scat_k(const int* __restrict__ src,
                                              const int* __restrict__ dst,
                                              const float* __restrict__ dinv,
                                              int* __restrict__ cur,
                                              const int* __restrict__ cbase,
                                              int2* __restrict__ pr, int N, int E) {
    int idx = blockIdx.x * 256 + threadIdx.x;
    int stride = gridDim.x * 256;
    int nv = E >> 2;
    const int4* s4 = (const int4*)src;
    const int4* d4 = (const int4*)dst;
    for (int i = idx; i < nv; i += stride) {
        int4 s = s4[i];
        int4 d = d4[i];
        scat1(s.x, d.x, dinv, cur, cbase, pr, N);
        scat1(s.y, d.y, dinv, cur, cbase, pr, N);
        scat1(s.z, d.z, dinv, cur, cbase, pr, N);
        scat1(s.w, d.w, dinv, cur, cbase, pr, N);
    }
    for (int e = (nv << 2) + idx; e < E; e += stride)
        scat1(src[e], dst[e], dinv, cur, cbase, pr, N);
}

// ---------------- dense GEMM via MFMA 16x16x32 bf16: hout = in @ W ------------

__device__ __forceinline__ void gemm_body(bf8v Af0, bf8v Af1, const bf8v Bf[2][4],
                                          u16* __restrict__ hout, int base, int m,
                                          int quad, int N) {
    f4v acc[4] = {{0.f, 0.f, 0.f, 0.f},
                  {0.f, 0.f, 0.f, 0.f},
                  {0.f, 0.f, 0.f, 0.f},
                  {0.f, 0.f, 0.f, 0.f}};
#pragma unroll
    for (int nb = 0; nb < 4; ++nb)
        acc[nb] = __builtin_amdgcn_mfma_f32_16x16x32_bf16(Af0, Bf[0][nb], acc[nb], 0, 0, 0);
#pragma unroll
    for (int nb = 0; nb < 4; ++nb)
        acc[nb] = __builtin_amdgcn_mfma_f32_16x16x32_bf16(Af1, Bf[1][nb], acc[nb], 0, 0, 0);
#pragma unroll
    for (int nb = 0; nb < 4; ++nb)
#pragma unroll
        for (int r = 0; r < 4; ++r) {
            int rowi = base + quad * 4 + r;
            if (rowi < N) hout[(size_t)rowi * D + nb * 16 + m] = (u16)bf_rne(acc[nb][r]);
        }
}

__device__ __forceinline__ void load_B(const float* __restrict__ W, bf8v Bf[2][4], int m,
                                       int quad) {
#pragma unroll
    for (int kc = 0; kc < 2; ++kc)
#pragma unroll
        for (int nb = 0; nb < 4; ++nb)
#pragma unroll
            for (int j = 0; j < 8; ++j)
                Bf[kc][nb][j] = (short)bf_rne(W[(32 * kc + 8 * quad + j) * D + m + 16 * nb]);
}

__global__ __launch_bounds__(256) void gemm_k(const u32* __restrict__ hb,
                                              const float* __restrict__ W,
                                              u16* __restrict__ hout, int N) {
    int t = threadIdx.x;
    int lane = t & 63;
    int m = lane & 15;
    int quad = lane >> 4;
    bf8v Bf[2][4];
    load_B(W, Bf, m, quad);
    int ngroups = (N + 15) >> 4;
    int g = blockIdx.x * 4 + (t >> 6);
    int stride = gridDim.x * 4;
    for (; g < ngroups; g += stride) {
        int base = g * 16;
        int r0 = base + m;
        if (r0 >= N) r0 = N - 1;
        bf8v Af0 = *(const bf8v*)(hb + (size_t)r0 * 32 + quad * 4);
        bf8v Af1 = *(const bf8v*)(hb + (size_t)r0 * 32 + 16 + quad * 4);
        gemm_body(Af0, Af1, Bf, hout, base, m, quad, N);
    }
}

__global__ __launch_bounds__(256) void gemm_f32_k(const float* __restrict__ xf,
                                                  const float* __restrict__ W,
                                                  u16* __restrict__ hout, int N) {
    int t = threadIdx.x;
    int lane = t & 63;
    int m = lane & 15;
    int quad = lane >> 4;
    bf8v Bf[2][4];
    load_B(W, Bf, m, quad);
    int ngroups = (N + 15) >> 4;
    int g = blockIdx.x * 4 + (t >> 6);
    int stride = gridDim.x * 4;
    for (; g < ngroups; g += stride) {
        int base = g * 16;
        int r0 = base + m;
        if (r0 >= N) r0 = N - 1;
        const float* rp = xf + (size_t)r0 * D;
        float4 a0 = *(const float4*)(rp + quad * 8);
        float4 a1 = *(const float4*)(rp + quad * 8 + 4);
        float4 a2 = *(const float4*)(rp + 32 + quad * 8);
        float4 a3 = *(const float4*)(rp + 32 + quad * 8 + 4);
        bf8v Af0, Af1;
        Af0[0] = (short)bf_rne(a0.x); Af0[1] = (short)bf_rne(a0.y);
        Af0[2] = (short)bf_rne(a0.z); Af0[3] = (short)bf_rne(a0.w);
        Af0[4] = (short)bf_rne(a1.x); Af0[5] = (short)bf_rne(a1.y);
        Af0[6] = (short)bf_rne(a1.z); Af0[7] = (short)bf_rne(a1.w);
        Af1[0] = (short)bf_rne(a2.x); Af1[1] = (short)bf_rne(a2.y);
        Af1[2] = (short)bf_rne(a2.z); Af1[3] = (short)bf_rne(a2.w);
        Af1[4] = (short)bf_rne(a3.x); Af1[5] = (short)bf_rne(a3.y);
        Af1[6] = (short)bf_rne(a3.z); Af1[7] = (short)bf_rne(a3.w);
        gemm_body(Af0, Af1, Bf, hout, base, m, quad, N);
    }
}

// NOTE: parameter renamed gt/wt — a param named `w` would macro-substitute
// into the member access `.w` (R13 compile failure).
#define FMA4(gt, wt)                                                            \
    v0 = fmaf(bf_lo((gt).x), (wt), v0); v1 = fmaf(bf_hi((gt).x), (wt), v1);     \
    v2 = fmaf(bf_lo((gt).y), (wt), v2); v3 = fmaf(bf_hi((gt).y), (wt), v3);     \
    v4 = fmaf(bf_lo((gt).z), (wt), v4); v5 = fmaf(bf_hi((gt).z), (wt), v5);     \
    v6 = fmaf(bf_lo((gt).w), (wt), v6); v7 = fmaf(bf_hi((gt).w), (wt), v7);

// ---------------- lean gather: out = relu( A_norm @ h + b ) ----------------
// TWO nodes per wave (SLOTS=16): lanes 0-31 own node 2i, lanes 32-63 own node
// 2i+1. p = lane&7 picks 8 packed bf16 features; qh = (lane>>3)&3 handles
// slots {2qh,2qh+1,8+2qh,8+2qh+1}. Cross-iteration prefetch of next pair's pr.
__global__ __launch_bounds__(256) void agg_k(const uint4* __restrict__ h4,
                                             const int2* __restrict__ pr,
                                             const float* __restrict__ b,
                                             float* __restrict__ out_f32,
                                             u16* __restrict__ out_b16, int N) {
    int t = threadIdx.x;
    int lane = t & 63;
    int p = lane & 7;
    int qh = (lane >> 3) & 3;
    int hh = lane >> 5;
    int fsel = (lane & 32) | 31;  // per-half broadcast src (lane 31 / lane 63)
    float4 ba = *(const float4*)(b + 8 * p);
    float4 bb = *(const float4*)(b + 8 * p + 4);
    int npair = (N + 1) >> 1;
    int wid = blockIdx.x * 4 + (t >> 6);
    int nw = gridDim.x * 4;
    if (wid >= npair) return;
    int n0 = wid * 2 + hh;
    if (n0 >= N) n0 = N - 1;
    const int4* bp0 = (const int4*)(pr + (size_t)n0 * SLOTS);
    int4 pel0 = bp0[qh];
    int4 pel1 = bp0[qh + 4];
    for (int i = wid; i < npair; i += nw) {
        int n = 2 * i + hh;
        if (n >= N) n = N - 1;
        int4 el0 = pel0;
        int4 el1 = pel1;
        uint4 g0 = h4[(size_t)(u32)el0.x * 8 + p];
        uint4 g1 = h4[(size_t)(u32)el0.z * 8 + p];
        uint4 g2 = h4[(size_t)(u32)el1.x * 8 + p];
        uint4 g3 = h4[(size_t)(u32)el1.z * 8 + p];
        {
            int j = i + nw;
            int jn = (j < npair) ? (2 * j + hh) : n;
            if (jn >= N) jn = N - 1;
            const int4* bpn = (const int4*)(pr + (size_t)jn * SLOTS);
            pel0 = bpn[qh];
            pel1 = bpn[qh + 4];
        }
        float v0 = 0.f, v1 = 0.f, v2 = 0.f, v3 = 0.f;
        float v4 = 0.f, v5 = 0.f, v6 = 0.f, v7 = 0.f;
        FMA4(g0, __int_as_float(el0.y));
        FMA4(g1, __int_as_float(el0.w));
        FMA4(g2, __int_as_float(el1.y));
        FMA4(g3, __int_as_float(el1.w));
        // chain path (deg > 14): half-uniform flag; idle half does +0.0 self work
        int flag = __shfl(el1.w, fsel, 64);
        int cc = __shfl(el1.z, fsel, 64);
        while (__any(flag < 0)) {
            int4 e0, e1;
            if (flag < 0) {
                const int4* bpc =
                    (const int4*)(pr + (size_t)N * SLOTS + (size_t)cc * SLOTS);
                e0 = bpc[qh];
                e1 = bpc[qh + 4];
            } else {
                e0 = make_int4(n, 0, n, 0);  // +0.0 no-op, gathers L1-hot self row
                e1 = make_int4(n, 0, n, 0);
            }
            g0 = h4[(size_t)(u32)e0.x * 8 + p];
            g1 = h4[(size_t)(u32)e0.z * 8 + p];
            g2 = h4[(size_t)(u32)e1.x * 8 + p];
            g3 = h4[(size_t)(u32)e1.z * 8 + p];
            FMA4(g0, __int_as_float(e0.y));
            FMA4(g1, __int_as_float(e0.w));
            FMA4(g2, __int_as_float(e1.y));
            FMA4(g3, __int_as_float(e1.w));
            flag = __shfl(e1.w, fsel, 64);
            cc = __shfl(e1.z, fsel, 64);
        }
        // reduce over qh within each 32-lane half
        v0 += __shfl_xor(v0, 8, 64);  v1 += __shfl_xor(v1, 8, 64);
        v2 += __shfl_xor(v2, 8, 64);  v3 += __shfl_xor(v3, 8, 64);
        v4 += __shfl_xor(v4, 8, 64);  v5 += __shfl_xor(v5, 8, 64);
        v6 += __shfl_xor(v6, 8, 64);  v7 += __shfl_xor(v7, 8, 64);
        v0 += __shfl_xor(v0, 16, 64); v1 += __shfl_xor(v1, 16, 64);
        v2 += __shfl_xor(v2, 16, 64); v3 += __shfl_xor(v3, 16, 64);
        v4 += __shfl_xor(v4, 16, 64); v5 += __shfl_xor(v5, 16, 64);
        v6 += __shfl_xor(v6, 16, 64); v7 += __shfl_xor(v7, 16, 64);
        v0 = fmaxf(v0 + ba.x, 0.f); v1 = fmaxf(v1 + ba.y, 0.f);
        v2 = fmaxf(v2 + ba.z, 0.f); v3 = fmaxf(v3 + ba.w, 0.f);
        v4 = fmaxf(v4 + bb.x, 0.f); v5 = fmaxf(v5 + bb.y, 0.f);
        v6 = fmaxf(v6 + bb.z, 0.f); v7 = fmaxf(v7 + bb.w, 0.f);
        if (qh == 0) {
            if (out_b16) {
                uint4 o;
                o.x = bf_rne(v0) | (bf_rne(v1) << 16);
                o.y = bf_rne(v2) | (bf_rne(v3) << 16);
                o.z = bf_rne(v4) | (bf_rne(v5) << 16);
                o.w = bf_rne(v6) | (bf_rne(v7) << 16);
                *(uint4*)(out_b16 + (size_t)n * D + 8 * p) = o;
            } else {
                float* dst = out_f32 + (size_t)n * D + 8 * p;
                *(float4*)dst = make_float4(v0, v1, v2, v3);
                *(float4*)(dst + 4) = make_float4(v4, v5, v6, v7);
            }
        }
    }
}

// ---------------- launch ----------------

extern "C" void kernel_launch(void* const* d_in, const int* in_sizes, int n_in,
                              void* d_out, int out_size, void* d_ws, size_t ws_size,
                              hipStream_t stream) {
    const float* x  = (const float*)d_in[0];
    const int*   ei = (const int*)d_in[1];
    const float* W1 = (const float*)d_in[2];
    const float* b1 = (const float*)d_in[3];
    const float* W2 = (const float*)d_in[4];
    const float* b2 = (const float*)d_in[5];
    float* out = (float*)d_out;

    int N = in_sizes[0] / D;
    int E = in_sizes[1] / 2;
    const int* src = ei;
    const int* dst = ei + E;

    char* ws = (char*)d_ws;
    size_t off = 0;
    auto align256 = [](size_t v) { return (v + 255) & ~(size_t)255; };
    int* cnt = (int*)(ws + off);       off += align256((size_t)N * 4);
    int* ovf = (int*)(ws + off);       off += 256;        // contiguous with cnt: one memset
    size_t zbytes = off;                                  // cnt + ovf
    int* cur = (int*)(ws + off);       off += align256((size_t)N * 4);
    int* cbase = (int*)(ws + off);     off += align256((size_t)N * 4);
    float* dinv = (float*)(ws + off);  off += align256((size_t)N * 4);
    int2* pr = (int2*)(ws + off);      off += align256(((size_t)N + MAXCONT) * SLOTS * 8);
    u16* h = (u16*)(ws + off);         off += align256((size_t)N * D * 2);
    u16* buf16 = (u16*)(ws + off);     off += align256((size_t)N * D * 2);

    dim3 b256(256);

    // build pr adjacency (no sort): count -> coalesced init -> direct scatter
    hipMemsetAsync(cnt, 0, zbytes, stream);
    cnt_k<<<1024, b256, 0, stream>>>(dst, cnt, E);
    int initb = (N * 8 + 255) / 256;
    init_k<<<initb, b256, 0, stream>>>(cnt, dinv, cur, cbase, pr, ovf, N);
    scat_k<<<1024, b256, 0, stream>>>(src, dst, dinv, cur, cbase, pr, N, E);

    int ngroups = (N + 15) / 16;
    int gemm_blocks = (ngroups + 3) / 4;

    // layer 1: h = x @ W1 (fused f32->bf16 cast) ; buf16 = bf16(relu(agg(h)+b1))
    gemm_f32_k<<<gemm_blocks, b256, 0, stream>>>(x, W1, h, N);
    agg_k<<<2560, b256, 0, stream>>>((const uint4*)h, pr, b1, nullptr, buf16, N);
    // layer 2: h = buf16 @ W2 ; out = relu(agg(h) + b2)
    gemm_k<<<gemm_blocks, b256, 0, stream>>>((const u32*)buf16, W2, h, N);
    agg_k<<<2560, b256, 0, stream>>>((const uint4*)h, pr, b2, out, nullptr, N);
}

// Round 3
// 266.450 us; speedup vs baseline: 1.1916x; 1.1916x over previous
//
#include <hip/hip_runtime.h>

#define D 64
#define SLOTS 16    // fixed pr slots per node (slot0 self + 14 edges + chain/pad)
#define NOVF 256    // sharded chain allocators
#define CPER 272    // chain blocks per shard (MAXCONT/NOVF); expected use ~32
#define MAXCONT (NOVF * CPER)

typedef unsigned int u32;
typedef unsigned short u16;
typedef short bf8v __attribute__((ext_vector_type(8)));
typedef float f4v __attribute__((ext_vector_type(4)));

__device__ __forceinline__ float bf_lo(u32 p) { return __uint_as_float(p << 16); }
__device__ __forceinline__ float bf_hi(u32 p) { return __uint_as_float(p & 0xffff0000u); }
__device__ __forceinline__ u32 bf_rne(float f) {
    u32 u = __float_as_uint(f);
    return (u + 0x7fffu + ((u >> 16) & 1u)) >> 16;
}

// ---------------- pass 1: per-node degree via global atomics ----------------
// cnt zeroed by memsetAsync beforehand. 1M atomics over 100K counters: L2-resident.
__global__ __launch_bounds__(256) void cnt_k(const int* __restrict__ dst,
                                             int* __restrict__ cnt, int E) {
    int idx = blockIdx.x * 256 + threadIdx.x;
    int stride = gridDim.x * 256;
    int nv = E >> 2;
    const int4* d4 = (const int4*)dst;
    for (int i = idx; i < nv; i += stride) {
        int4 d = d4[i];
        atomicAdd(&cnt[d.x], 1);
        atomicAdd(&cnt[d.y], 1);
        atomicAdd(&cnt[d.z], 1);
        atomicAdd(&cnt[d.w], 1);
    }
    for (int e = (nv << 2) + idx; e < E; e += stride) atomicAdd(&cnt[dst[e]], 1);
}

// ---------------- pass 2: coalesced slot-block init ----------------
// 8 threads per node; thread (node,j) writes pr slots {2j,2j+1} as one int4 at
// flat index node*8+j -> perfect coalescing. j==0 does per-node bookkeeping.
// Chain-block allocation is SHARDED 256 ways (R2 post-mortem: a single ovf
// counter's same-address atomic-with-return serialized ~94% of waves, 75 us).
// Shard s owns chain blocks [s*CPER, (s+1)*CPER); node uses shard node&255 ->
// consecutive nodes hit distinct counters, ~32 expected allocs per shard.
__global__ __launch_bounds__(256) void init_k(const int* __restrict__ cnt,
                                              float* __restrict__ dinv,
                                              int* __restrict__ cur,
                                              int* __restrict__ cbase,
                                              int2* __restrict__ pr,
                                              int* __restrict__ ovf, int N) {
    int idx = blockIdx.x * 256 + threadIdx.x;
    int lane = threadIdx.x & 63;
    int node = idx >> 3;
    int j = idx & 7;
    bool valid = node < N;
    int c = valid ? cnt[node] : 0;
    float di = rsqrtf((float)c + 1.0f);
    int nblk = (c > 14) ? (c / 15) : 0;
    int cb = 0;
    if (valid && j == 0) {
        if (nblk) cb = (node & (NOVF - 1)) * CPER + atomicAdd(&ovf[node & (NOVF - 1)], nblk);
        dinv[node] = di;
        cur[node] = 1;
        cbase[node] = cb;
        // chain region: blocks cb..cb+nblk-1, 15 payload pads + link at slot15
        for (int k = 0; k < nblk; ++k) {
            int2* blk = pr + ((size_t)N + (size_t)(cb + k)) * SLOTS;
            int4 pad = make_int4(node, 0, node, 0);
            int4* b4 = (int4*)blk;
            b4[0] = pad; b4[1] = pad; b4[2] = pad; b4[3] = pad;
            b4[4] = pad; b4[5] = pad; b4[6] = pad;
            blk[14] = make_int2(node, 0);
            blk[15] = (k < nblk - 1) ? make_int2(cb + k + 1, (int)0x80000000u)
                                     : make_int2(node, 0);
        }
    }
    cb = __shfl(cb, lane & 56, 64);  // broadcast from the j==0 lane of this node
    if (!valid) return;
    int4 v;
    if (j == 0)
        v = make_int4(node, __float_as_int(di * di), node, 0);
    else if (j == 7)
        v = nblk ? make_int4(node, 0, cb, (int)0x80000000u)
                 : make_int4(node, 0, node, 0);
    else
        v = make_int4(node, 0, node, 0);
    ((int4*)pr)[idx] = v;
}

// ---------------- pass 3: direct edge scatter into slots ----------------
__device__ __forceinline__ void scat1(int s, int d, const float* __restrict__ dinv,
                                      int* __restrict__ cur,
                                      const int* __restrict__ cbase,
                                      int2* __restrict__ pr, int N) {
    int pos = atomicAdd(&cur[d], 1);
    float w = dinv[s] * dinv[d];
    size_t phys;
    if (pos < 15) {
        phys = (size_t)d * SLOTS + pos;
    } else {
        int r = pos - 15;
        phys = ((size_t)N + (size_t)(cbase[d] + r / 15)) * SLOTS + (r % 15);
    }
    pr[phys] = make_int2(s, __float_as_int(w));
}

__global__ __launch_bounds__(256) void scat_k(const int* __restrict__ src,
                                              const int* __restrict__ dst,
                                              const float* __restrict__ dinv,
                                              int* __restrict__ cur,
                                              const int* __restrict__ cbase,
                                              int2* __restrict__ pr, int N, int E) {
    int idx = blockIdx.x * 256 + threadIdx.x;
    int stride = gridDim.x * 256;
    int nv = E >> 2;
    const int4* s4 = (const int4*)src;
    const int4* d4 = (const int4*)dst;
    for (int i = idx; i < nv; i += stride) {
        int4 s = s4[i];
        int4 d = d4[i];
        scat1(s.x, d.x, dinv, cur, cbase, pr, N);
        scat1(s.y, d.y, dinv, cur, cbase, pr, N);
        scat1(s.z, d.z, dinv, cur, cbase, pr, N);
        scat1(s.w, d.w, dinv, cur, cbase, pr, N);
    }
    for (int e = (nv << 2) + idx; e < E; e += stride)
        scat1(src[e], dst[e], dinv, cur, cbase, pr, N);
}

// ---------------- dense GEMM via MFMA 16x16x32 bf16: hout = in @ W ------------

__device__ __forceinline__ void gemm_body(bf8v Af0, bf8v Af1, const bf8v Bf[2][4],
                                          u16* __restrict__ hout, int base, int m,
                                          int quad, int N) {
    f4v acc[4] = {{0.f, 0.f, 0.f, 0.f},
                  {0.f, 0.f, 0.f, 0.f},
                  {0.f, 0.f, 0.f, 0.f},
                  {0.f, 0.f, 0.f, 0.f}};
#pragma unroll
    for (int nb = 0; nb < 4; ++nb)
        acc[nb] = __builtin_amdgcn_mfma_f32_16x16x32_bf16(Af0, Bf[0][nb], acc[nb], 0, 0, 0);
#pragma unroll
    for (int nb = 0; nb < 4; ++nb)
        acc[nb] = __builtin_amdgcn_mfma_f32_16x16x32_bf16(Af1, Bf[1][nb], acc[nb], 0, 0, 0);
#pragma unroll
    for (int nb = 0; nb < 4; ++nb)
#pragma unroll
        for (int r = 0; r < 4; ++r) {
            int rowi = base + quad * 4 + r;
            if (rowi < N) hout[(size_t)rowi * D + nb * 16 + m] = (u16)bf_rne(acc[nb][r]);
        }
}

__device__ __forceinline__ void load_B(const float* __restrict__ W, bf8v Bf[2][4], int m,
                                       int quad) {
#pragma unroll
    for (int kc = 0; kc < 2; ++kc)
#pragma unroll
        for (int nb = 0; nb < 4; ++nb)
#pragma unroll
            for (int j = 0; j < 8; ++j)
                Bf[kc][nb][j] = (short)bf_rne(W[(32 * kc + 8 * quad + j) * D + m + 16 * nb]);
}

__global__ __launch_bounds__(256) void gemm_k(const u32* __restrict__ hb,
                                              const float* __restrict__ W,
                                              u16* __restrict__ hout, int N) {
    int t = threadIdx.x;
    int lane = t & 63;
    int m = lane & 15;
    int quad = lane >> 4;
    bf8v Bf[2][4];
    load_B(W, Bf, m, quad);
    int ngroups = (N + 15) >> 4;
    int g = blockIdx.x * 4 + (t >> 6);
    int stride = gridDim.x * 4;
    for (; g < ngroups; g += stride) {
        int base = g * 16;
        int r0 = base + m;
        if (r0 >= N) r0 = N - 1;
        bf8v Af0 = *(const bf8v*)(hb + (size_t)r0 * 32 + quad * 4);
        bf8v Af1 = *(const bf8v*)(hb + (size_t)r0 * 32 + 16 + quad * 4);
        gemm_body(Af0, Af1, Bf, hout, base, m, quad, N);
    }
}

__global__ __launch_bounds__(256) void gemm_f32_k(const float* __restrict__ xf,
                                                  const float* __restrict__ W,
                                                  u16* __restrict__ hout, int N) {
    int t = threadIdx.x;
    int lane = t & 63;
    int m = lane & 15;
    int quad = lane >> 4;
    bf8v Bf[2][4];
    load_B(W, Bf, m, quad);
    int ngroups = (N + 15) >> 4;
    int g = blockIdx.x * 4 + (t >> 6);
    int stride = gridDim.x * 4;
    for (; g < ngroups; g += stride) {
        int base = g * 16;
        int r0 = base + m;
        if (r0 >= N) r0 = N - 1;
        const float* rp = xf + (size_t)r0 * D;
        float4 a0 = *(const float4*)(rp + quad * 8);
        float4 a1 = *(const float4*)(rp + quad * 8 + 4);
        float4 a2 = *(const float4*)(rp + 32 + quad * 8);
        float4 a3 = *(const float4*)(rp + 32 + quad * 8 + 4);
        bf8v Af0, Af1;
        Af0[0] = (short)bf_rne(a0.x); Af0[1] = (short)bf_rne(a0.y);
        Af0[2] = (short)bf_rne(a0.z); Af0[3] = (short)bf_rne(a0.w);
        Af0[4] = (short)bf_rne(a1.x); Af0[5] = (short)bf_rne(a1.y);
        Af0[6] = (short)bf_rne(a1.z); Af0[7] = (short)bf_rne(a1.w);
        Af1[0] = (short)bf_rne(a2.x); Af1[1] = (short)bf_rne(a2.y);
        Af1[2] = (short)bf_rne(a2.z); Af1[3] = (short)bf_rne(a2.w);
        Af1[4] = (short)bf_rne(a3.x); Af1[5] = (short)bf_rne(a3.y);
        Af1[6] = (short)bf_rne(a3.z); Af1[7] = (short)bf_rne(a3.w);
        gemm_body(Af0, Af1, Bf, hout, base, m, quad, N);
    }
}

// NOTE: parameter renamed gt/wt — a param named `w` would macro-substitute
// into the member access `.w` (R13 compile failure).
#define FMA4(gt, wt)                                                            \
    v0 = fmaf(bf_lo((gt).x), (wt), v0); v1 = fmaf(bf_hi((gt).x), (wt), v1);     \
    v2 = fmaf(bf_lo((gt).y), (wt), v2); v3 = fmaf(bf_hi((gt).y), (wt), v3);     \
    v4 = fmaf(bf_lo((gt).z), (wt), v4); v5 = fmaf(bf_hi((gt).z), (wt), v5);     \
    v6 = fmaf(bf_lo((gt).w), (wt), v6); v7 = fmaf(bf_hi((gt).w), (wt), v7);

// ---------------- lean gather: out = relu( A_norm @ h + b ) ----------------
// TWO nodes per wave (SLOTS=16): lanes 0-31 own node 2i, lanes 32-63 own node
// 2i+1. p = lane&7 picks 8 packed bf16 features; qh = (lane>>3)&3 handles
// slots {2qh,2qh+1,8+2qh,8+2qh+1}. Cross-iteration prefetch of next pair's pr.
__global__ __launch_bounds__(256) void agg_k(const uint4* __restrict__ h4,
                                             const int2* __restrict__ pr,
                                             const float* __restrict__ b,
                                             float* __restrict__ out_f32,
                                             u16* __restrict__ out_b16, int N) {
    int t = threadIdx.x;
    int lane = t & 63;
    int p = lane & 7;
    int qh = (lane >> 3) & 3;
    int hh = lane >> 5;
    int fsel = (lane & 32) | 31;  // per-half broadcast src (lane 31 / lane 63)
    float4 ba = *(const float4*)(b + 8 * p);
    float4 bb = *(const float4*)(b + 8 * p + 4);
    int npair = (N + 1) >> 1;
    int wid = blockIdx.x * 4 + (t >> 6);
    int nw = gridDim.x * 4;
    if (wid >= npair) return;
    int n0 = wid * 2 + hh;
    if (n0 >= N) n0 = N - 1;
    const int4* bp0 = (const int4*)(pr + (size_t)n0 * SLOTS);
    int4 pel0 = bp0[qh];
    int4 pel1 = bp0[qh + 4];
    for (int i = wid; i < npair; i += nw) {
        int n = 2 * i + hh;
        if (n >= N) n = N - 1;
        int4 el0 = pel0;
        int4 el1 = pel1;
        uint4 g0 = h4[(size_t)(u32)el0.x * 8 + p];
        uint4 g1 = h4[(size_t)(u32)el0.z * 8 + p];
        uint4 g2 = h4[(size_t)(u32)el1.x * 8 + p];
        uint4 g3 = h4[(size_t)(u32)el1.z * 8 + p];
        {
            int j = i + nw;
            int jn = (j < npair) ? (2 * j + hh) : n;
            if (jn >= N) jn = N - 1;
            const int4* bpn = (const int4*)(pr + (size_t)jn * SLOTS);
            pel0 = bpn[qh];
            pel1 = bpn[qh + 4];
        }
        float v0 = 0.f, v1 = 0.f, v2 = 0.f, v3 = 0.f;
        float v4 = 0.f, v5 = 0.f, v6 = 0.f, v7 = 0.f;
        FMA4(g0, __int_as_float(el0.y));
        FMA4(g1, __int_as_float(el0.w));
        FMA4(g2, __int_as_float(el1.y));
        FMA4(g3, __int_as_float(el1.w));
        // chain path (deg > 14): half-uniform flag; idle half does +0.0 self work
        int flag = __shfl(el1.w, fsel, 64);
        int cc = __shfl(el1.z, fsel, 64);
        while (__any(flag < 0)) {
            int4 e0, e1;
            if (flag < 0) {
                const int4* bpc =
                    (const int4*)(pr + (size_t)N * SLOTS + (size_t)cc * SLOTS);
                e0 = bpc[qh];
                e1 = bpc[qh + 4];
            } else {
                e0 = make_int4(n, 0, n, 0);  // +0.0 no-op, gathers L1-hot self row
                e1 = make_int4(n, 0, n, 0);
            }
            g0 = h4[(size_t)(u32)e0.x * 8 + p];
            g1 = h4[(size_t)(u32)e0.z * 8 + p];
            g2 = h4[(size_t)(u32)e1.x * 8 + p];
            g3 = h4[(size_t)(u32)e1.z * 8 + p];
            FMA4(g0, __int_as_float(e0.y));
            FMA4(g1, __int_as_float(e0.w));
            FMA4(g2, __int_as_float(e1.y));
            FMA4(g3, __int_as_float(e1.w));
            flag = __shfl(e1.w, fsel, 64);
            cc = __shfl(e1.z, fsel, 64);
        }
        // reduce over qh within each 32-lane half
        v0 += __shfl_xor(v0, 8, 64);  v1 += __shfl_xor(v1, 8, 64);
        v2 += __shfl_xor(v2, 8, 64);  v3 += __shfl_xor(v3, 8, 64);
        v4 += __shfl_xor(v4, 8, 64);  v5 += __shfl_xor(v5, 8, 64);
        v6 += __shfl_xor(v6, 8, 64);  v7 += __shfl_xor(v7, 8, 64);
        v0 += __shfl_xor(v0, 16, 64); v1 += __shfl_xor(v1, 16, 64);
        v2 += __shfl_xor(v2, 16, 64); v3 += __shfl_xor(v3, 16, 64);
        v4 += __shfl_xor(v4, 16, 64); v5 += __shfl_xor(v5, 16, 64);
        v6 += __shfl_xor(v6, 16, 64); v7 += __shfl_xor(v7, 16, 64);
        v0 = fmaxf(v0 + ba.x, 0.f); v1 = fmaxf(v1 + ba.y, 0.f);
        v2 = fmaxf(v2 + ba.z, 0.f); v3 = fmaxf(v3 + ba.w, 0.f);
        v4 = fmaxf(v4 + bb.x, 0.f); v5 = fmaxf(v5 + bb.y, 0.f);
        v6 = fmaxf(v6 + bb.z, 0.f); v7 = fmaxf(v7 + bb.w, 0.f);
        if (qh == 0) {
            if (out_b16) {
                uint4 o;
                o.x = bf_rne(v0) | (bf_rne(v1) << 16);
                o.y = bf_rne(v2) | (bf_rne(v3) << 16);
                o.z = bf_rne(v4) | (bf_rne(v5) << 16);
                o.w = bf_rne(v6) | (bf_rne(v7) << 16);
                *(uint4*)(out_b16 + (size_t)n * D + 8 * p) = o;
            } else {
                float* dst = out_f32 + (size_t)n * D + 8 * p;
                *(float4*)dst = make_float4(v0, v1, v2, v3);
                *(float4*)(dst + 4) = make_float4(v4, v5, v6, v7);
            }
        }
    }
}

// ---------------- launch ----------------

extern "C" void kernel_launch(void* const* d_in, const int* in_sizes, int n_in,
                              void* d_out, int out_size, void* d_ws, size_t ws_size,
                              hipStream_t stream) {
    const float* x  = (const float*)d_in[0];
    const int*   ei = (const int*)d_in[1];
    const float* W1 = (const float*)d_in[2];
    const float* b1 = (const float*)d_in[3];
    const float* W2 = (const float*)d_in[4];
    const float* b2 = (const float*)d_in[5];
    float* out = (float*)d_out;

    int N = in_sizes[0] / D;
    int E = in_sizes[1] / 2;
    const int* src = ei;
    const int* dst = ei + E;

    char* ws = (char*)d_ws;
    size_t off = 0;
    auto align256 = [](size_t v) { return (v + 255) & ~(size_t)255; };
    int* cnt = (int*)(ws + off);       off += align256((size_t)N * 4);
    int* ovf = (int*)(ws + off);       off += align256(NOVF * 4);  // in memset span
    size_t zbytes = off;                                           // cnt + ovf
    int* cur = (int*)(ws + off);       off += align256((size_t)N * 4);
    int* cbase = (int*)(ws + off);     off += align256((size_t)N * 4);
    float* dinv = (float*)(ws + off);  off += align256((size_t)N * 4);
    int2* pr = (int2*)(ws + off);      off += align256(((size_t)N + MAXCONT) * SLOTS * 8);
    u16* h = (u16*)(ws + off);         off += align256((size_t)N * D * 2);
    u16* buf16 = (u16*)(ws + off);     off += align256((size_t)N * D * 2);

    dim3 b256(256);

    // build pr adjacency (no sort): count -> coalesced init -> direct scatter
    hipMemsetAsync(cnt, 0, zbytes, stream);
    cnt_k<<<2048, b256, 0, stream>>>(dst, cnt, E);
    int initb = (N * 8 + 255) / 256;
    init_k<<<initb, b256, 0, stream>>>(cnt, dinv, cur, cbase, pr, ovf, N);
    scat_k<<<2048, b256, 0, stream>>>(src, dst, dinv, cur, cbase, pr, N, E);

    int ngroups = (N + 15) / 16;
    int gemm_blocks = (ngroups + 3) / 4;

    // layer 1: h = x @ W1 (fused f32->bf16 cast) ; buf16 = bf16(relu(agg(h)+b1))
    gemm_f32_k<<<gemm_blocks, b256, 0, stream>>>(x, W1, h, N);
    agg_k<<<2560, b256, 0, stream>>>((const uint4*)h, pr, b1, nullptr, buf16, N);
    // layer 2: h = buf16 @ W2 ; out = relu(agg(h) + b2)
    gemm_k<<<gemm_blocks, b256, 0, stream>>>((const u32*)buf16, W2, h, N);
    agg_k<<<2560, b256, 0, stream>>>((const uint4*)h, pr, b2, out, nullptr, N);
}

// Round 4
// 199.337 us; speedup vs baseline: 1.5928x; 1.3367x over previous
//
#include <hip/hip_runtime.h>

#define D 64
#define NB 256      // partition blocks for hist/scatter
#define BSHIFT 8    // bucket = 256 nodes
#define SLOTS 16    // fixed pr slots per node (slot0 self + 14 edges + chain/pad)
#define NOVF 256    // sharded chain allocators (R2 lesson: single counter = 75us)
#define CPER 272    // chain blocks per shard; expected use ~32
#define MAXCONT (NOVF * CPER)

typedef unsigned int u32;
typedef unsigned short u16;
typedef short bf8v __attribute__((ext_vector_type(8)));
typedef float f4v __attribute__((ext_vector_type(4)));

__device__ __forceinline__ float bf_lo(u32 p) { return __uint_as_float(p << 16); }
__device__ __forceinline__ float bf_hi(u32 p) { return __uint_as_float(p & 0xffff0000u); }
__device__ __forceinline__ u32 bf_rne(float f) {
    u32 u = __float_as_uint(f);
    return (u + 0x7fffu + ((u >> 16) & 1u)) >> 16;
}

// ---------------- pass A: per-block bucket histogram (LDS atomics only) --------
__global__ __launch_bounds__(256) void hist_k(const int* __restrict__ dst,
                                              int* __restrict__ histT, int E, int chunk,
                                              int nbuck) {
    __shared__ int h[512];
    int t = threadIdx.x;
    for (int b = t; b < nbuck; b += 256) h[b] = 0;
    __syncthreads();
    int start = blockIdx.x * chunk;
    int endi = min(E, start + chunk);
    for (int j = start + t; j < endi; j += 256) atomicAdd(&h[dst[j] >> BSHIFT], 1);
    __syncthreads();
    for (int b = t; b < nbuck; b += 256) histT[b * NB + blockIdx.x] = h[b];
}

// ---------------- generic grid scan (for histT); also zeroes ovf shards -------
__global__ __launch_bounds__(1024) void gscan1_k(const int* __restrict__ in,
                                                 int* __restrict__ out,
                                                 int* __restrict__ partials,
                                                 int* __restrict__ ovf, int M) {
    __shared__ int wsum[16];
    int t = threadIdx.x, wave = t >> 6, lane = t & 63;
    if (blockIdx.x == 0 && t < NOVF) ovf[t] = 0;  // runs well before bfill2
    int i = blockIdx.x * 1024 + t;
    int v = (i < M) ? in[i] : 0;
    int x = v;
#pragma unroll
    for (int off = 1; off < 64; off <<= 1) {
        int y = __shfl_up(x, off, 64);
        if (lane >= off) x += y;
    }
    if (lane == 63) wsum[wave] = x;
    __syncthreads();
    if (wave == 0) {
        int s = (lane < 16) ? wsum[lane] : 0;
#pragma unroll
        for (int off = 1; off < 16; off <<= 1) {
            int y = __shfl_up(s, off, 64);
            if (lane >= off) s += y;
        }
        if (lane < 16) wsum[lane] = s;
    }
    __syncthreads();
    int woff = (wave > 0) ? wsum[wave - 1] : 0;
    if (i < M) out[i] = x + woff - v;
    if (t == 0) partials[blockIdx.x] = wsum[15];
}

__global__ __launch_bounds__(128) void scan2_k(const int* __restrict__ partials,
                                               int* __restrict__ blockoff,
                                               int* __restrict__ totalp, int nb) {
    __shared__ int s[128];
    int t = threadIdx.x;
    int v = (t < nb) ? partials[t] : 0;
    s[t] = v;
    __syncthreads();
    for (int off = 1; off < 128; off <<= 1) {
        int add = (t >= off) ? s[t - off] : 0;
        __syncthreads();
        s[t] += add;
        __syncthreads();
    }
    blockoff[t] = s[t] - v;
    if (t == nb - 1) *totalp = s[t];
}

// seg(x) = histT[x] + blockoff2[x>>10]
__device__ __forceinline__ int seg_at(const int* __restrict__ histT,
                                      const int* __restrict__ blockoff2, int x) {
    return histT[x] + blockoff2[x >> 10];
}

// ---------------- pass B: scatter edges into bucket-sorted segments ----------
// Packed 4B entries: src in bits 0..23 (<2^17 used), dst&255 in bits 24..31.
__global__ __launch_bounds__(256) void bscat_k(const int* __restrict__ src,
                                               const int* __restrict__ dst,
                                               const int* __restrict__ histT,
                                               const int* __restrict__ blockoff2,
                                               u32* __restrict__ pairs, int E, int chunk,
                                               int nbuck) {
    __shared__ int sbase[512];
    __shared__ int rank[512];
    int t = threadIdx.x;
    for (int b = t; b < nbuck; b += 256) {
        sbase[b] = seg_at(histT, blockoff2, b * NB + blockIdx.x);
        rank[b] = 0;
    }
    __syncthreads();
    int start = blockIdx.x * chunk;
    int endi = min(E, start + chunk);
    for (int j = start + t; j < endi; j += 256) {
        int d = dst[j];
        int b = d >> BSHIFT;
        int pos = sbase[b] + atomicAdd(&rank[b], 1);
        pairs[pos] = (u32)src[j] | ((u32)(d & 255) << 24);
    }
}

// ---------------- pass C1: per-node count (LDS) -> cnt + dinv ----------------
__global__ __launch_bounds__(256) void bcount_k(const u32* __restrict__ pairs,
                                                const int* __restrict__ histT,
                                                const int* __restrict__ blockoff2,
                                                int* __restrict__ cnt,
                                                float* __restrict__ dinv,
                                                int N, int nbuck, int E) {
    __shared__ int c[1 << BSHIFT];
    int t = threadIdx.x;
    int b = blockIdx.x;
    int base = b << BSHIFT;
    c[t] = 0;
    __syncthreads();
    int s0 = seg_at(histT, blockoff2, b * NB);
    int s1 = (b + 1 < nbuck) ? seg_at(histT, blockoff2, (b + 1) * NB) : E;
    for (int j = s0 + t; j < s1; j += 256) atomicAdd(&c[pairs[j] >> 24], 1);
    __syncthreads();
    int n = base + t;
    if (n < N) {
        cnt[n] = c[t];
        dinv[n] = rsqrtf((float)c[t] + 1.0f);
    }
}

// ---------------- pass C2: coalesced slot init + LDS-atomic edge scatter ------
// node n's slots: pr[16n..16n+15]; 0 = self (n, dinv^2), 1..14 = edges/pads,
// 15 = pad (n,+0.0) or chain (cb, -0.0). Chain blocks at pr+16N: 15 payload +
// link. Init phase writes the bucket's whole contiguous region as int4s
// (coalesced, pads everywhere); scatter phase overwrites pads via LDS cur.
__global__ __launch_bounds__(256) void bfill2_k(const u32* __restrict__ pairs,
                                                const int* __restrict__ histT,
                                                const int* __restrict__ blockoff2,
                                                const int* __restrict__ cnt,
                                                const float* __restrict__ dinv,
                                                int2* __restrict__ pr,
                                                int* __restrict__ ovf,
                                                int N, int nbuck, int E) {
    __shared__ int lcur[1 << BSHIFT];
    __shared__ int lcb[1 << BSHIFT];
    __shared__ int lnb[1 << BSHIFT];
    __shared__ float ldv[1 << BSHIFT];
    int t = threadIdx.x;
    int b = blockIdx.x;
    int base = b << BSHIFT;
    int n = base + t;
    int nvalid = min(256, N - base);
    int nblk = 0, cb = 0;
    float di = 0.f;
    if (t < nvalid) {
        int c = cnt[n];
        di = dinv[n];
        nblk = (c > 14) ? (c / 15) : 0;
        if (nblk) {
            cb = (n & (NOVF - 1)) * CPER + atomicAdd(&ovf[n & (NOVF - 1)], nblk);
            // rare chain-region init (deg>14, ~8% of nodes)
            for (int k = 0; k < nblk; ++k) {
                int2* blk = pr + ((size_t)N + (size_t)(cb + k)) * SLOTS;
                int4 pad = make_int4(n, 0, n, 0);
                int4* b4 = (int4*)blk;
                b4[0] = pad; b4[1] = pad; b4[2] = pad; b4[3] = pad;
                b4[4] = pad; b4[5] = pad; b4[6] = pad;
                blk[14] = make_int2(n, 0);
                blk[15] = (k < nblk - 1) ? make_int2(cb + k + 1, (int)0x80000000u)
                                         : make_int2(n, 0);
            }
        }
    }
    lcur[t] = 1;
    lcb[t] = cb;
    lnb[t] = nblk;
    ldv[t] = di;
    __syncthreads();
    // coalesced main-region init: nvalid*8 int4s, contiguous
    int4* mb = (int4*)(pr + (size_t)base * SLOTS);
    int nint4 = nvalid * 8;
    for (int f = t; f < nint4; f += 256) {
        int nd = f >> 3, j = f & 7;
        int node = base + nd;
        int4 v;
        if (j == 0) {
            float dd = ldv[nd];
            v = make_int4(node, __float_as_int(dd * dd), node, 0);
        } else if (j == 7) {
            v = lnb[nd] ? make_int4(node, 0, lcb[nd], (int)0x80000000u)
                        : make_int4(node, 0, node, 0);
        } else {
            v = make_int4(node, 0, node, 0);
        }
        mb[f] = v;
    }
    __syncthreads();
    int s0 = seg_at(histT, blockoff2, b * NB);
    int s1 = (b + 1 < nbuck) ? seg_at(histT, blockoff2, (b + 1) * NB) : E;
    for (int j = s0 + t; j < s1; j += 256) {
        u32 pe = pairs[j];
        int s = (int)(pe & 0x00FFFFFFu);
        int dloc = (int)(pe >> 24);
        int pos = atomicAdd(&lcur[dloc], 1);
        float w = dinv[s] * ldv[dloc];
        size_t phys;
        if (pos < 15) {
            phys = (size_t)(base + dloc) * SLOTS + pos;
        } else {
            int r = pos - 15;
            phys = ((size_t)N + (size_t)(lcb[dloc] + r / 15)) * SLOTS + (r % 15);
        }
        pr[phys] = make_int2(s, __float_as_int(w));
    }
}

// ---------------- dense GEMM via MFMA 16x16x32 bf16: hout = in @ W ------------

__device__ __forceinline__ void gemm_body(bf8v Af0, bf8v Af1, const bf8v Bf[2][4],
                                          u16* __restrict__ hout, int base, int m,
                                          int quad, int N) {
    f4v acc[4] = {{0.f, 0.f, 0.f, 0.f},
                  {0.f, 0.f, 0.f, 0.f},
                  {0.f, 0.f, 0.f, 0.f},
                  {0.f, 0.f, 0.f, 0.f}};
#pragma unroll
    for (int nb = 0; nb < 4; ++nb)
        acc[nb] = __builtin_amdgcn_mfma_f32_16x16x32_bf16(Af0, Bf[0][nb], acc[nb], 0, 0, 0);
#pragma unroll
    for (int nb = 0; nb < 4; ++nb)
        acc[nb] = __builtin_amdgcn_mfma_f32_16x16x32_bf16(Af1, Bf[1][nb], acc[nb], 0, 0, 0);
#pragma unroll
    for (int nb = 0; nb < 4; ++nb)
#pragma unroll
        for (int r = 0; r < 4; ++r) {
            int rowi = base + quad * 4 + r;
            if (rowi < N) hout[(size_t)rowi * D + nb * 16 + m] = (u16)bf_rne(acc[nb][r]);
        }
}

__device__ __forceinline__ void load_B(const float* __restrict__ W, bf8v Bf[2][4], int m,
                                       int quad) {
#pragma unroll
    for (int kc = 0; kc < 2; ++kc)
#pragma unroll
        for (int nb = 0; nb < 4; ++nb)
#pragma unroll
            for (int j = 0; j < 8; ++j)
                Bf[kc][nb][j] = (short)bf_rne(W[(32 * kc + 8 * quad + j) * D + m + 16 * nb]);
}

__global__ __launch_bounds__(256) void gemm_k(const u32* __restrict__ hb,
                                              const float* __restrict__ W,
                                              u16* __restrict__ hout, int N) {
    int t = threadIdx.x;
    int lane = t & 63;
    int m = lane & 15;
    int quad = lane >> 4;
    bf8v Bf[2][4];
    load_B(W, Bf, m, quad);
    int ngroups = (N + 15) >> 4;
    int g = blockIdx.x * 4 + (t >> 6);
    int stride = gridDim.x * 4;
    for (; g < ngroups; g += stride) {
        int base = g * 16;
        int r0 = base + m;
        if (r0 >= N) r0 = N - 1;
        bf8v Af0 = *(const bf8v*)(hb + (size_t)r0 * 32 + quad * 4);
        bf8v Af1 = *(const bf8v*)(hb + (size_t)r0 * 32 + 16 + quad * 4);
        gemm_body(Af0, Af1, Bf, hout, base, m, quad, N);
    }
}

__global__ __launch_bounds__(256) void gemm_f32_k(const float* __restrict__ xf,
                                                  const float* __restrict__ W,
                                                  u16* __restrict__ hout, int N) {
    int t = threadIdx.x;
    int lane = t & 63;
    int m = lane & 15;
    int quad = lane >> 4;
    bf8v Bf[2][4];
    load_B(W, Bf, m, quad);
    int ngroups = (N + 15) >> 4;
    int g = blockIdx.x * 4 + (t >> 6);
    int stride = gridDim.x * 4;
    for (; g < ngroups; g += stride) {
        int base = g * 16;
        int r0 = base + m;
        if (r0 >= N) r0 = N - 1;
        const float* rp = xf + (size_t)r0 * D;
        float4 a0 = *(const float4*)(rp + quad * 8);
        float4 a1 = *(const float4*)(rp + quad * 8 + 4);
        float4 a2 = *(const float4*)(rp + 32 + quad * 8);
        float4 a3 = *(const float4*)(rp + 32 + quad * 8 + 4);
        bf8v Af0, Af1;
        Af0[0] = (short)bf_rne(a0.x); Af0[1] = (short)bf_rne(a0.y);
        Af0[2] = (short)bf_rne(a0.z); Af0[3] = (short)bf_rne(a0.w);
        Af0[4] = (short)bf_rne(a1.x); Af0[5] = (short)bf_rne(a1.y);
        Af0[6] = (short)bf_rne(a1.z); Af0[7] = (short)bf_rne(a1.w);
        Af1[0] = (short)bf_rne(a2.x); Af1[1] = (short)bf_rne(a2.y);
        Af1[2] = (short)bf_rne(a2.z); Af1[3] = (short)bf_rne(a2.w);
        Af1[4] = (short)bf_rne(a3.x); Af1[5] = (short)bf_rne(a3.y);
        Af1[6] = (short)bf_rne(a3.z); Af1[7] = (short)bf_rne(a3.w);
        gemm_body(Af0, Af1, Bf, hout, base, m, quad, N);
    }
}

// NOTE: parameter renamed gt/wt — a param named `w` would macro-substitute
// into the member access `.w` (R13 compile failure).
#define FMA4(gt, wt)                                                            \
    v0 = fmaf(bf_lo((gt).x), (wt), v0); v1 = fmaf(bf_hi((gt).x), (wt), v1);     \
    v2 = fmaf(bf_lo((gt).y), (wt), v2); v3 = fmaf(bf_hi((gt).y), (wt), v3);     \
    v4 = fmaf(bf_lo((gt).z), (wt), v4); v5 = fmaf(bf_hi((gt).z), (wt), v5);     \
    v6 = fmaf(bf_lo((gt).w), (wt), v6); v7 = fmaf(bf_hi((gt).w), (wt), v7);

// ---------------- lean gather: out = relu( A_norm @ h + b ) ----------------
// TWO nodes per wave (SLOTS=16): lanes 0-31 own node 2i, lanes 32-63 own node
// 2i+1. p = lane&7 picks 8 packed bf16 features; qh = (lane>>3)&3 handles
// slots {2qh,2qh+1,8+2qh,8+2qh+1}. Cross-iteration prefetch of next pair's pr.
__global__ __launch_bounds__(256) void agg_k(const uint4* __restrict__ h4,
                                             const int2* __restrict__ pr,
                                             const float* __restrict__ b,
                                             float* __restrict__ out_f32,
                                             u16* __restrict__ out_b16, int N) {
    int t = threadIdx.x;
    int lane = t & 63;
    int p = lane & 7;
    int qh = (lane >> 3) & 3;
    int hh = lane >> 5;
    int fsel = (lane & 32) | 31;  // per-half broadcast src (lane 31 / lane 63)
    float4 ba = *(const float4*)(b + 8 * p);
    float4 bb = *(const float4*)(b + 8 * p + 4);
    int npair = (N + 1) >> 1;
    int wid = blockIdx.x * 4 + (t >> 6);
    int nw = gridDim.x * 4;
    if (wid >= npair) return;
    int n0 = wid * 2 + hh;
    if (n0 >= N) n0 = N - 1;
    const int4* bp0 = (const int4*)(pr + (size_t)n0 * SLOTS);
    int4 pel0 = bp0[qh];
    int4 pel1 = bp0[qh + 4];
    for (int i = wid; i < npair; i += nw) {
        int n = 2 * i + hh;
        if (n >= N) n = N - 1;
        int4 el0 = pel0;
        int4 el1 = pel1;
        uint4 g0 = h4[(size_t)(u32)el0.x * 8 + p];
        uint4 g1 = h4[(size_t)(u32)el0.z * 8 + p];
        uint4 g2 = h4[(size_t)(u32)el1.x * 8 + p];
        uint4 g3 = h4[(size_t)(u32)el1.z * 8 + p];
        {
            int j = i + nw;
            int jn = (j < npair) ? (2 * j + hh) : n;
            if (jn >= N) jn = N - 1;
            const int4* bpn = (const int4*)(pr + (size_t)jn * SLOTS);
            pel0 = bpn[qh];
            pel1 = bpn[qh + 4];
        }
        float v0 = 0.f, v1 = 0.f, v2 = 0.f, v3 = 0.f;
        float v4 = 0.f, v5 = 0.f, v6 = 0.f, v7 = 0.f;
        FMA4(g0, __int_as_float(el0.y));
        FMA4(g1, __int_as_float(el0.w));
        FMA4(g2, __int_as_float(el1.y));
        FMA4(g3, __int_as_float(el1.w));
        // chain path (deg > 14): half-uniform flag; idle half does +0.0 self work
        int flag = __shfl(el1.w, fsel, 64);
        int cc = __shfl(el1.z, fsel, 64);
        while (__any(flag < 0)) {
            int4 e0, e1;
            if (flag < 0) {
                const int4* bpc =
                    (const int4*)(pr + (size_t)N * SLOTS + (size_t)cc * SLOTS);
                e0 = bpc[qh];
                e1 = bpc[qh + 4];
            } else {
                e0 = make_int4(n, 0, n, 0);  // +0.0 no-op, gathers L1-hot self row
                e1 = make_int4(n, 0, n, 0);
            }
            g0 = h4[(size_t)(u32)e0.x * 8 + p];
            g1 = h4[(size_t)(u32)e0.z * 8 + p];
            g2 = h4[(size_t)(u32)e1.x * 8 + p];
            g3 = h4[(size_t)(u32)e1.z * 8 + p];
            FMA4(g0, __int_as_float(e0.y));
            FMA4(g1, __int_as_float(e0.w));
            FMA4(g2, __int_as_float(e1.y));
            FMA4(g3, __int_as_float(e1.w));
            flag = __shfl(e1.w, fsel, 64);
            cc = __shfl(e1.z, fsel, 64);
        }
        // reduce over qh within each 32-lane half
        v0 += __shfl_xor(v0, 8, 64);  v1 += __shfl_xor(v1, 8, 64);
        v2 += __shfl_xor(v2, 8, 64);  v3 += __shfl_xor(v3, 8, 64);
        v4 += __shfl_xor(v4, 8, 64);  v5 += __shfl_xor(v5, 8, 64);
        v6 += __shfl_xor(v6, 8, 64);  v7 += __shfl_xor(v7, 8, 64);
        v0 += __shfl_xor(v0, 16, 64); v1 += __shfl_xor(v1, 16, 64);
        v2 += __shfl_xor(v2, 16, 64); v3 += __shfl_xor(v3, 16, 64);
        v4 += __shfl_xor(v4, 16, 64); v5 += __shfl_xor(v5, 16, 64);
        v6 += __shfl_xor(v6, 16, 64); v7 += __shfl_xor(v7, 16, 64);
        v0 = fmaxf(v0 + ba.x, 0.f); v1 = fmaxf(v1 + ba.y, 0.f);
        v2 = fmaxf(v2 + ba.z, 0.f); v3 = fmaxf(v3 + ba.w, 0.f);
        v4 = fmaxf(v4 + bb.x, 0.f); v5 = fmaxf(v5 + bb.y, 0.f);
        v6 = fmaxf(v6 + bb.z, 0.f); v7 = fmaxf(v7 + bb.w, 0.f);
        if (qh == 0) {
            if (out_b16) {
                uint4 o;
                o.x = bf_rne(v0) | (bf_rne(v1) << 16);
                o.y = bf_rne(v2) | (bf_rne(v3) << 16);
                o.z = bf_rne(v4) | (bf_rne(v5) << 16);
                o.w = bf_rne(v6) | (bf_rne(v7) << 16);
                *(uint4*)(out_b16 + (size_t)n * D + 8 * p) = o;
            } else {
                float* dst = out_f32 + (size_t)n * D + 8 * p;
                *(float4*)dst = make_float4(v0, v1, v2, v3);
                *(float4*)(dst + 4) = make_float4(v4, v5, v6, v7);
            }
        }
    }
}

// ---------------- launch ----------------

extern "C" void kernel_launch(void* const* d_in, const int* in_sizes, int n_in,
                              void* d_out, int out_size, void* d_ws, size_t ws_size,
                              hipStream_t stream) {
    const float* x  = (const float*)d_in[0];
    const int*   ei = (const int*)d_in[1];
    const float* W1 = (const float*)d_in[2];
    const float* b1 = (const float*)d_in[3];
    const float* W2 = (const float*)d_in[4];
    const float* b2 = (const float*)d_in[5];
    float* out = (float*)d_out;

    int N = in_sizes[0] / D;
    int E = in_sizes[1] / 2;
    const int* src = ei;
    const int* dst = ei + E;

    int nbuck = (N + (1 << BSHIFT) - 1) >> BSHIFT;  // 391
    int chunk = (E + NB - 1) / NB;
    int M = nbuck * NB;

    char* ws = (char*)d_ws;
    size_t off = 0;
    auto align256 = [](size_t v) { return (v + 255) & ~(size_t)255; };
    int* cnt = (int*)(ws + off);       off += align256((size_t)N * 4);
    float* dinv = (float*)(ws + off);  off += align256((size_t)N * 4);
    int* partials2 = (int*)(ws + off); off += 512;
    int* blockoff2 = (int*)(ws + off); off += 512;
    int* scratch = (int*)(ws + off);   off += 256;
    int* ovf = (int*)(ws + off);       off += align256(NOVF * 4);
    int* histT = (int*)(ws + off);     off += align256((size_t)M * 4);
    u32* pairs = (u32*)(ws + off);     off += align256((size_t)E * 4);
    int2* pr = (int2*)(ws + off);      off += align256(((size_t)N + MAXCONT) * SLOTS * 8);
    u16* h = (u16*)(ws + off);         off += align256((size_t)N * D * 2);
    u16* buf16 = (u16*)(ws + off);     off += align256((size_t)N * D * 2);

    dim3 b256(256);
    int nbG = (M + 1023) / 1024;  // hist-scan blocks (98)

    hist_k<<<NB, b256, 0, stream>>>(dst, histT, E, chunk, nbuck);
    gscan1_k<<<nbG, 1024, 0, stream>>>(histT, histT, partials2, ovf, M);
    scan2_k<<<1, 128, 0, stream>>>(partials2, blockoff2, scratch, nbG);
    bscat_k<<<NB, b256, 0, stream>>>(src, dst, histT, blockoff2, pairs, E, chunk, nbuck);
    bcount_k<<<nbuck, b256, 0, stream>>>(pairs, histT, blockoff2, cnt, dinv, N, nbuck, E);
    bfill2_k<<<nbuck, b256, 0, stream>>>(pairs, histT, blockoff2, cnt, dinv, pr, ovf, N,
                                         nbuck, E);

    int ngroups = (N + 15) / 16;
    int gemm_blocks = (ngroups + 3) / 4;

    // layer 1: h = x @ W1 (fused f32->bf16 cast) ; buf16 = bf16(relu(agg(h)+b1))
    gemm_f32_k<<<gemm_blocks, b256, 0, stream>>>(x, W1, h, N);
    agg_k<<<2560, b256, 0, stream>>>((const uint4*)h, pr, b1, nullptr, buf16, N);
    // layer 2: h = buf16 @ W2 ; out = relu(agg(h) + b2)
    gemm_k<<<gemm_blocks, b256, 0, stream>>>((const u32*)buf16, W2, h, N);
    agg_k<<<2560, b256, 0, stream>>>((const uint4*)h, pr, b2, out, nullptr, N);
}

// Round 5
// 197.723 us; speedup vs baseline: 1.6058x; 1.0082x over previous
//
#include <hip/hip_runtime.h>

#define D 64
#define NB 256      // partition blocks for hist/scatter
#define BSHIFT 8    // bucket = 256 nodes
#define SLOTS 16    // fixed pr slots per node (slot0 self + 14 edges + chain/pad)
#define NOVF 256    // sharded chain allocators (R2 lesson: single counter = 75us)
#define CPER 272    // chain blocks per shard; expected use ~32
#define MAXCONT (NOVF * CPER)

typedef unsigned int u32;
typedef unsigned short u16;
typedef short bf8v __attribute__((ext_vector_type(8)));
typedef float f4v __attribute__((ext_vector_type(4)));

__device__ __forceinline__ float bf_lo(u32 p) { return __uint_as_float(p << 16); }
__device__ __forceinline__ float bf_hi(u32 p) { return __uint_as_float(p & 0xffff0000u); }
__device__ __forceinline__ u32 bf_rne(float f) {
    u32 u = __float_as_uint(f);
    return (u + 0x7fffu + ((u >> 16) & 1u)) >> 16;
}

// ---------------- pass A: per-block bucket histogram (LDS atomics only) --------
// block 0 also zeroes the ovf shards + the scan done-counter (consumed later).
__global__ __launch_bounds__(256) void hist_k(const int* __restrict__ dst,
                                              int* __restrict__ histT, int E, int chunk,
                                              int nbuck, int* __restrict__ ovf,
                                              int* __restrict__ donecnt) {
    __shared__ int h[512];
    int t = threadIdx.x;
    if (blockIdx.x == 0) {
        if (t < NOVF) ovf[t] = 0;
        if (t == 0) *donecnt = 0;
    }
    for (int b = t; b < nbuck; b += 256) h[b] = 0;
    __syncthreads();
    int start = blockIdx.x * chunk;
    int endi = min(E, start + chunk);
    for (int j = start + t; j < endi; j += 256) atomicAdd(&h[dst[j] >> BSHIFT], 1);
    __syncthreads();
    for (int b = t; b < nbuck; b += 256) histT[b * NB + blockIdx.x] = h[b];
}

// ---------------- grid scan for histT, scan2 FOLDED IN (last-block-done) ------
// Each block: exclusive scan of its 1024 elems + partial sum. The last block to
// finish (device-scope atomic) scans the <=128 partials into blockoff. Removes
// the 1-block scan2 dispatch + its serial bubble.
__global__ __launch_bounds__(1024) void gscan1_k(const int* __restrict__ in,
                                                 int* __restrict__ out,
                                                 int* __restrict__ partials,
                                                 int* __restrict__ blockoff,
                                                 int* __restrict__ donecnt, int M) {
    __shared__ int wsum[16];
    __shared__ int ps[128];
    __shared__ int lastflag;
    int t = threadIdx.x, wave = t >> 6, lane = t & 63;
    int i = blockIdx.x * 1024 + t;
    int v = (i < M) ? in[i] : 0;
    int x = v;
#pragma unroll
    for (int off = 1; off < 64; off <<= 1) {
        int y = __shfl_up(x, off, 64);
        if (lane >= off) x += y;
    }
    if (lane == 63) wsum[wave] = x;
    __syncthreads();
    if (wave == 0) {
        int s = (lane < 16) ? wsum[lane] : 0;
#pragma unroll
        for (int off = 1; off < 16; off <<= 1) {
            int y = __shfl_up(s, off, 64);
            if (lane >= off) s += y;
        }
        if (lane < 16) wsum[lane] = s;
    }
    __syncthreads();
    int woff = (wave > 0) ? wsum[wave - 1] : 0;
    if (i < M) out[i] = x + woff - v;
    if (t == 0) {
        partials[blockIdx.x] = wsum[15];
        __threadfence();  // release partials before signaling
        int prev = atomicAdd(donecnt, 1);
        lastflag = (prev == (int)gridDim.x - 1);
    }
    __syncthreads();
    if (lastflag) {  // block-uniform branch: barriers inside are legal
        int nb = gridDim.x;
        if (t < 128) ps[t] = (t < nb) ? partials[t] : 0;
        __syncthreads();
        for (int off = 1; off < 128; off <<= 1) {
            int add = (t < 128 && t >= off) ? ps[t - off] : 0;
            __syncthreads();
            if (t < 128) ps[t] += add;
            __syncthreads();
        }
        if (t < 128) blockoff[t] = ps[t] - ((t < nb) ? partials[t] : 0);
    }
}

// seg(x) = histT[x] + blockoff2[x>>10]
__device__ __forceinline__ int seg_at(const int* __restrict__ histT,
                                      const int* __restrict__ blockoff2, int x) {
    return histT[x] + blockoff2[x >> 10];
}

__device__ __forceinline__ void gemm_body(bf8v Af0, bf8v Af1, const bf8v Bf[2][4],
                                          u16* __restrict__ hout, int base, int m,
                                          int quad, int N) {
    f4v acc[4] = {{0.f, 0.f, 0.f, 0.f},
                  {0.f, 0.f, 0.f, 0.f},
                  {0.f, 0.f, 0.f, 0.f},
                  {0.f, 0.f, 0.f, 0.f}};
#pragma unroll
    for (int nb = 0; nb < 4; ++nb)
        acc[nb] = __builtin_amdgcn_mfma_f32_16x16x32_bf16(Af0, Bf[0][nb], acc[nb], 0, 0, 0);
#pragma unroll
    for (int nb = 0; nb < 4; ++nb)
        acc[nb] = __builtin_amdgcn_mfma_f32_16x16x32_bf16(Af1, Bf[1][nb], acc[nb], 0, 0, 0);
#pragma unroll
    for (int nb = 0; nb < 4; ++nb)
#pragma unroll
        for (int r = 0; r < 4; ++r) {
            int rowi = base + quad * 4 + r;
            if (rowi < N) hout[(size_t)rowi * D + nb * 16 + m] = (u16)bf_rne(acc[nb][r]);
        }
}

__device__ __forceinline__ void load_B(const float* __restrict__ W, bf8v Bf[2][4], int m,
                                       int quad) {
#pragma unroll
    for (int kc = 0; kc < 2; ++kc)
#pragma unroll
        for (int nb = 0; nb < 4; ++nb)
#pragma unroll
            for (int j = 0; j < 8; ++j)
                Bf[kc][nb][j] = (short)bf_rne(W[(32 * kc + 8 * quad + j) * D + m + 16 * nb]);
}

// ---------------- pass B + layer-1 GEMM, role-split grid ----------------
// Blocks < nbs: scatter edges into bucket-sorted segments (packed 4B entries:
// src in bits 0..23, dst&255 in bits 24..31). Blocks >= nbs: gemm_f32 body
// (h = bf16(x @ W1)) grid-strided. The two are independent; fusing overlaps
// gemm1's ~7us under bscat instead of serializing on the stream.
__global__ __launch_bounds__(256) void bscat_gemm_k(
    const int* __restrict__ src, const int* __restrict__ dst,
    const int* __restrict__ histT, const int* __restrict__ blockoff2,
    u32* __restrict__ pairs, int E, int chunk, int nbuck,
    const float* __restrict__ xf, const float* __restrict__ W,
    u16* __restrict__ hout, int N, int nbs) {
    __shared__ int sbase[512];
    __shared__ int rank[512];
    int t = threadIdx.x;
    if ((int)blockIdx.x < nbs) {
        for (int b = t; b < nbuck; b += 256) {
            sbase[b] = seg_at(histT, blockoff2, b * NB + blockIdx.x);
            rank[b] = 0;
        }
        __syncthreads();
        int start = blockIdx.x * chunk;
        int endi = min(E, start + chunk);
        for (int j = start + t; j < endi; j += 256) {
            int d = dst[j];
            int b = d >> BSHIFT;
            int pos = sbase[b] + atomicAdd(&rank[b], 1);
            pairs[pos] = (u32)src[j] | ((u32)(d & 255) << 24);
        }
    } else {
        int lane = t & 63;
        int m = lane & 15;
        int quad = lane >> 4;
        bf8v Bf[2][4];
        load_B(W, Bf, m, quad);
        int ngroups = (N + 15) >> 4;
        int g = ((int)blockIdx.x - nbs) * 4 + (t >> 6);
        int stride = ((int)gridDim.x - nbs) * 4;
        for (; g < ngroups; g += stride) {
            int base = g * 16;
            int r0 = base + m;
            if (r0 >= N) r0 = N - 1;
            const float* rp = xf + (size_t)r0 * D;
            float4 a0 = *(const float4*)(rp + quad * 8);
            float4 a1 = *(const float4*)(rp + quad * 8 + 4);
            float4 a2 = *(const float4*)(rp + 32 + quad * 8);
            float4 a3 = *(const float4*)(rp + 32 + quad * 8 + 4);
            bf8v Af0, Af1;
            Af0[0] = (short)bf_rne(a0.x); Af0[1] = (short)bf_rne(a0.y);
            Af0[2] = (short)bf_rne(a0.z); Af0[3] = (short)bf_rne(a0.w);
            Af0[4] = (short)bf_rne(a1.x); Af0[5] = (short)bf_rne(a1.y);
            Af0[6] = (short)bf_rne(a1.z); Af0[7] = (short)bf_rne(a1.w);
            Af1[0] = (short)bf_rne(a2.x); Af1[1] = (short)bf_rne(a2.y);
            Af1[2] = (short)bf_rne(a2.z); Af1[3] = (short)bf_rne(a2.w);
            Af1[4] = (short)bf_rne(a3.x); Af1[5] = (short)bf_rne(a3.y);
            Af1[6] = (short)bf_rne(a3.z); Af1[7] = (short)bf_rne(a3.w);
            gemm_body(Af0, Af1, Bf, hout, base, m, quad, N);
        }
    }
}

// ---------------- pass C1: per-node count (LDS) -> cnt + dinv ----------------
__global__ __launch_bounds__(256) void bcount_k(const u32* __restrict__ pairs,
                                                const int* __restrict__ histT,
                                                const int* __restrict__ blockoff2,
                                                int* __restrict__ cnt,
                                                float* __restrict__ dinv,
                                                int N, int nbuck, int E) {
    __shared__ int c[1 << BSHIFT];
    int t = threadIdx.x;
    int b = blockIdx.x;
    int base = b << BSHIFT;
    c[t] = 0;
    __syncthreads();
    int s0 = seg_at(histT, blockoff2, b * NB);
    int s1 = (b + 1 < nbuck) ? seg_at(histT, blockoff2, (b + 1) * NB) : E;
    for (int j = s0 + t; j < s1; j += 256) atomicAdd(&c[pairs[j] >> 24], 1);
    __syncthreads();
    int n = base + t;
    if (n < N) {
        cnt[n] = c[t];
        dinv[n] = rsqrtf((float)c[t] + 1.0f);
    }
}

// ---------------- pass C2: coalesced slot init + LDS-atomic edge scatter ------
// node n's slots: pr[16n..16n+15]; 0 = self (n, dinv^2), 1..14 = edges/pads,
// 15 = pad (n,+0.0) or chain (cb, -0.0). Chain blocks at pr+16N: 15 payload +
// link. Init phase writes the bucket's whole contiguous region as int4s
// (coalesced, pads everywhere); scatter phase overwrites pads via LDS cur.
__global__ __launch_bounds__(256) void bfill2_k(const u32* __restrict__ pairs,
                                                const int* __restrict__ histT,
                                                const int* __restrict__ blockoff2,
                                                const int* __restrict__ cnt,
                                                const float* __restrict__ dinv,
                                                int2* __restrict__ pr,
                                                int* __restrict__ ovf,
                                                int N, int nbuck, int E) {
    __shared__ int lcur[1 << BSHIFT];
    __shared__ int lcb[1 << BSHIFT];
    __shared__ int lnb[1 << BSHIFT];
    __shared__ float ldv[1 << BSHIFT];
    int t = threadIdx.x;
    int b = blockIdx.x;
    int base = b << BSHIFT;
    int n = base + t;
    int nvalid = min(256, N - base);
    int nblk = 0, cb = 0;
    float di = 0.f;
    if (t < nvalid) {
        int c = cnt[n];
        di = dinv[n];
        nblk = (c > 14) ? (c / 15) : 0;
        if (nblk) {
            cb = (n & (NOVF - 1)) * CPER + atomicAdd(&ovf[n & (NOVF - 1)], nblk);
            // rare chain-region init (deg>14, ~8% of nodes)
            for (int k = 0; k < nblk; ++k) {
                int2* blk = pr + ((size_t)N + (size_t)(cb + k)) * SLOTS;
                int4 pad = make_int4(n, 0, n, 0);
                int4* b4 = (int4*)blk;
                b4[0] = pad; b4[1] = pad; b4[2] = pad; b4[3] = pad;
                b4[4] = pad; b4[5] = pad; b4[6] = pad;
                blk[14] = make_int2(n, 0);
                blk[15] = (k < nblk - 1) ? make_int2(cb + k + 1, (int)0x80000000u)
                                         : make_int2(n, 0);
            }
        }
    }
    lcur[t] = 1;
    lcb[t] = cb;
    lnb[t] = nblk;
    ldv[t] = di;
    __syncthreads();
    // coalesced main-region init: nvalid*8 int4s, contiguous
    int4* mb = (int4*)(pr + (size_t)base * SLOTS);
    int nint4 = nvalid * 8;
    for (int f = t; f < nint4; f += 256) {
        int nd = f >> 3, j = f & 7;
        int node = base + nd;
        int4 v;
        if (j == 0) {
            float dd = ldv[nd];
            v = make_int4(node, __float_as_int(dd * dd), node, 0);
        } else if (j == 7) {
            v = lnb[nd] ? make_int4(node, 0, lcb[nd], (int)0x80000000u)
                        : make_int4(node, 0, node, 0);
        } else {
            v = make_int4(node, 0, node, 0);
        }
        mb[f] = v;
    }
    __syncthreads();
    int s0 = seg_at(histT, blockoff2, b * NB);
    int s1 = (b + 1 < nbuck) ? seg_at(histT, blockoff2, (b + 1) * NB) : E;
    for (int j = s0 + t; j < s1; j += 256) {
        u32 pe = pairs[j];
        int s = (int)(pe & 0x00FFFFFFu);
        int dloc = (int)(pe >> 24);
        int pos = atomicAdd(&lcur[dloc], 1);
        float w = dinv[s] * ldv[dloc];
        size_t phys;
        if (pos < 15) {
            phys = (size_t)(base + dloc) * SLOTS + pos;
        } else {
            int r = pos - 15;
            phys = ((size_t)N + (size_t)(lcb[dloc] + r / 15)) * SLOTS + (r % 15);
        }
        pr[phys] = make_int2(s, __float_as_int(w));
    }
}

// ---------------- dense GEMM via MFMA (layer 2, bf16 input) -------------------
__global__ __launch_bounds__(256) void gemm_k(const u32* __restrict__ hb,
                                              const float* __restrict__ W,
                                              u16* __restrict__ hout, int N) {
    int t = threadIdx.x;
    int lane = t & 63;
    int m = lane & 15;
    int quad = lane >> 4;
    bf8v Bf[2][4];
    load_B(W, Bf, m, quad);
    int ngroups = (N + 15) >> 4;
    int g = blockIdx.x * 4 + (t >> 6);
    int stride = gridDim.x * 4;
    for (; g < ngroups; g += stride) {
        int base = g * 16;
        int r0 = base + m;
        if (r0 >= N) r0 = N - 1;
        bf8v Af0 = *(const bf8v*)(hb + (size_t)r0 * 32 + quad * 4);
        bf8v Af1 = *(const bf8v*)(hb + (size_t)r0 * 32 + 16 + quad * 4);
        gemm_body(Af0, Af1, Bf, hout, base, m, quad, N);
    }
}

// NOTE: parameter renamed gt/wt — a param named `w` would macro-substitute
// into the member access `.w` (R13 compile failure).
#define FMA4(gt, wt)                                                            \
    v0 = fmaf(bf_lo((gt).x), (wt), v0); v1 = fmaf(bf_hi((gt).x), (wt), v1);     \
    v2 = fmaf(bf_lo((gt).y), (wt), v2); v3 = fmaf(bf_hi((gt).y), (wt), v3);     \
    v4 = fmaf(bf_lo((gt).z), (wt), v4); v5 = fmaf(bf_hi((gt).z), (wt), v5);     \
    v6 = fmaf(bf_lo((gt).w), (wt), v6); v7 = fmaf(bf_hi((gt).w), (wt), v7);

// ---------------- lean gather: out = relu( A_norm @ h + b ) ----------------
// TWO nodes per wave (SLOTS=16): lanes 0-31 own node 2i, lanes 32-63 own node
// 2i+1. p = lane&7 picks 8 packed bf16 features; qh = (lane>>3)&3 handles
// slots {2qh,2qh+1,8+2qh,8+2qh+1}. Cross-iteration prefetch of next pair's pr.
__global__ __launch_bounds__(256) void agg_k(const uint4* __restrict__ h4,
                                             const int2* __restrict__ pr,
                                             const float* __restrict__ b,
                                             float* __restrict__ out_f32,
                                             u16* __restrict__ out_b16, int N) {
    int t = threadIdx.x;
    int lane = t & 63;
    int p = lane & 7;
    int qh = (lane >> 3) & 3;
    int hh = lane >> 5;
    int fsel = (lane & 32) | 31;  // per-half broadcast src (lane 31 / lane 63)
    float4 ba = *(const float4*)(b + 8 * p);
    float4 bb = *(const float4*)(b + 8 * p + 4);
    int npair = (N + 1) >> 1;
    int wid = blockIdx.x * 4 + (t >> 6);
    int nw = gridDim.x * 4;
    if (wid >= npair) return;
    int n0 = wid * 2 + hh;
    if (n0 >= N) n0 = N - 1;
    const int4* bp0 = (const int4*)(pr + (size_t)n0 * SLOTS);
    int4 pel0 = bp0[qh];
    int4 pel1 = bp0[qh + 4];
    for (int i = wid; i < npair; i += nw) {
        int n = 2 * i + hh;
        if (n >= N) n = N - 1;
        int4 el0 = pel0;
        int4 el1 = pel1;
        uint4 g0 = h4[(size_t)(u32)el0.x * 8 + p];
        uint4 g1 = h4[(size_t)(u32)el0.z * 8 + p];
        uint4 g2 = h4[(size_t)(u32)el1.x * 8 + p];
        uint4 g3 = h4[(size_t)(u32)el1.z * 8 + p];
        {
            int j = i + nw;
            int jn = (j < npair) ? (2 * j + hh) : n;
            if (jn >= N) jn = N - 1;
            const int4* bpn = (const int4*)(pr + (size_t)jn * SLOTS);
            pel0 = bpn[qh];
            pel1 = bpn[qh + 4];
        }
        float v0 = 0.f, v1 = 0.f, v2 = 0.f, v3 = 0.f;
        float v4 = 0.f, v5 = 0.f, v6 = 0.f, v7 = 0.f;
        FMA4(g0, __int_as_float(el0.y));
        FMA4(g1, __int_as_float(el0.w));
        FMA4(g2, __int_as_float(el1.y));
        FMA4(g3, __int_as_float(el1.w));
        // chain path (deg > 14): half-uniform flag; idle half does +0.0 self work
        int flag = __shfl(el1.w, fsel, 64);
        int cc = __shfl(el1.z, fsel, 64);
        while (__any(flag < 0)) {
            int4 e0, e1;
            if (flag < 0) {
                const int4* bpc =
                    (const int4*)(pr + (size_t)N * SLOTS + (size_t)cc * SLOTS);
                e0 = bpc[qh];
                e1 = bpc[qh + 4];
            } else {
                e0 = make_int4(n, 0, n, 0);  // +0.0 no-op, gathers L1-hot self row
                e1 = make_int4(n, 0, n, 0);
            }
            g0 = h4[(size_t)(u32)e0.x * 8 + p];
            g1 = h4[(size_t)(u32)e0.z * 8 + p];
            g2 = h4[(size_t)(u32)e1.x * 8 + p];
            g3 = h4[(size_t)(u32)e1.z * 8 + p];
            FMA4(g0, __int_as_float(e0.y));
            FMA4(g1, __int_as_float(e0.w));
            FMA4(g2, __int_as_float(e1.y));
            FMA4(g3, __int_as_float(e1.w));
            flag = __shfl(e1.w, fsel, 64);
            cc = __shfl(e1.z, fsel, 64);
        }
        // reduce over qh within each 32-lane half
        v0 += __shfl_xor(v0, 8, 64);  v1 += __shfl_xor(v1, 8, 64);
        v2 += __shfl_xor(v2, 8, 64);  v3 += __shfl_xor(v3, 8, 64);
        v4 += __shfl_xor(v4, 8, 64);  v5 += __shfl_xor(v5, 8, 64);
        v6 += __shfl_xor(v6, 8, 64);  v7 += __shfl_xor(v7, 8, 64);
        v0 += __shfl_xor(v0, 16, 64); v1 += __shfl_xor(v1, 16, 64);
        v2 += __shfl_xor(v2, 16, 64); v3 += __shfl_xor(v3, 16, 64);
        v4 += __shfl_xor(v4, 16, 64); v5 += __shfl_xor(v5, 16, 64);
        v6 += __shfl_xor(v6, 16, 64); v7 += __shfl_xor(v7, 16, 64);
        v0 = fmaxf(v0 + ba.x, 0.f); v1 = fmaxf(v1 + ba.y, 0.f);
        v2 = fmaxf(v2 + ba.z, 0.f); v3 = fmaxf(v3 + ba.w, 0.f);
        v4 = fmaxf(v4 + bb.x, 0.f); v5 = fmaxf(v5 + bb.y, 0.f);
        v6 = fmaxf(v6 + bb.z, 0.f); v7 = fmaxf(v7 + bb.w, 0.f);
        if (qh == 0) {
            if (out_b16) {
                uint4 o;
                o.x = bf_rne(v0) | (bf_rne(v1) << 16);
                o.y = bf_rne(v2) | (bf_rne(v3) << 16);
                o.z = bf_rne(v4) | (bf_rne(v5) << 16);
                o.w = bf_rne(v6) | (bf_rne(v7) << 16);
                *(uint4*)(out_b16 + (size_t)n * D + 8 * p) = o;
            } else {
                float* dst = out_f32 + (size_t)n * D + 8 * p;
                *(float4*)dst = make_float4(v0, v1, v2, v3);
                *(float4*)(dst + 4) = make_float4(v4, v5, v6, v7);
            }
        }
    }
}

// ---------------- launch ----------------

extern "C" void kernel_launch(void* const* d_in, const int* in_sizes, int n_in,
                              void* d_out, int out_size, void* d_ws, size_t ws_size,
                              hipStream_t stream) {
    const float* x  = (const float*)d_in[0];
    const int*   ei = (const int*)d_in[1];
    const float* W1 = (const float*)d_in[2];
    const float* b1 = (const float*)d_in[3];
    const float* W2 = (const float*)d_in[4];
    const float* b2 = (const float*)d_in[5];
    float* out = (float*)d_out;

    int N = in_sizes[0] / D;
    int E = in_sizes[1] / 2;
    const int* src = ei;
    const int* dst = ei + E;

    int nbuck = (N + (1 << BSHIFT) - 1) >> BSHIFT;  // 391
    int chunk = (E + NB - 1) / NB;
    int M = nbuck * NB;

    char* ws = (char*)d_ws;
    size_t off = 0;
    auto align256 = [](size_t v) { return (v + 255) & ~(size_t)255; };
    int* cnt = (int*)(ws + off);       off += align256((size_t)N * 4);
    float* dinv = (float*)(ws + off);  off += align256((size_t)N * 4);
    int* partials2 = (int*)(ws + off); off += 512;
    int* blockoff2 = (int*)(ws + off); off += 512;
    int* donecnt = (int*)(ws + off);   off += 256;
    int* ovf = (int*)(ws + off);       off += align256(NOVF * 4);
    int* histT = (int*)(ws + off);     off += align256((size_t)M * 4);
    u32* pairs = (u32*)(ws + off);     off += align256((size_t)E * 4);
    int2* pr = (int2*)(ws + off);      off += align256(((size_t)N + MAXCONT) * SLOTS * 8);
    u16* h = (u16*)(ws + off);         off += align256((size_t)N * D * 2);
    u16* buf16 = (u16*)(ws + off);     off += align256((size_t)N * D * 2);

    dim3 b256(256);
    int nbG = (M + 1023) / 1024;  // hist-scan blocks (98)
    int ngroups = (N + 15) / 16;
    int gemm_blocks = (ngroups + 3) / 4;

    hist_k<<<NB, b256, 0, stream>>>(dst, histT, E, chunk, nbuck, ovf, donecnt);
    gscan1_k<<<nbG, 1024, 0, stream>>>(histT, histT, partials2, blockoff2, donecnt, M);
    // bscat (blocks 0..NB-1) || layer-1 gemm_f32 (remaining blocks)
    bscat_gemm_k<<<NB + gemm_blocks, b256, 0, stream>>>(
        src, dst, histT, blockoff2, pairs, E, chunk, nbuck, x, W1, h, N, NB);
    bcount_k<<<nbuck, b256, 0, stream>>>(pairs, histT, blockoff2, cnt, dinv, N, nbuck, E);
    bfill2_k<<<nbuck, b256, 0, stream>>>(pairs, histT, blockoff2, cnt, dinv, pr, ovf, N,
                                         nbuck, E);

    // layer 1 agg: buf16 = bf16(relu(agg(h)+b1))
    agg_k<<<2560, b256, 0, stream>>>((const uint4*)h, pr, b1, nullptr, buf16, N);
    // layer 2: h = buf16 @ W2 ; out = relu(agg(h) + b2)
    gemm_k<<<gemm_blocks, b256, 0, stream>>>((const u32*)buf16, W2, h, N);
    agg_k<<<2560, b256, 0, stream>>>((const uint4*)h, pr, b2, out, nullptr, N);
}